// Round 1
// baseline (714.658 us; speedup 1.0000x reference)
//
#include <hip/hip_runtime.h>
#include <math.h>
#include <limits.h>

#define DIM   512
#define KSEL  64
#define NB1   64          // stage-1 blocks
#define SLOTS1 13         // ceil((N/NB1)/256) for N=200000 -> EPB=3125
#define SLOTS2 16         // (NB1*KSEL)/256 = 4096/256

// ---------------- Kernel 1: alpha[i] = dot(vs[i], v) ----------------
__global__ __launch_bounds__(256) void dot_kernel(const float* __restrict__ vs,
                                                  const float* __restrict__ v,
                                                  float* __restrict__ alpha,
                                                  int n) {
    const int lane = threadIdx.x & 63;
    const int waveInBlock = threadIdx.x >> 6;
    const int wavesPerBlock = blockDim.x >> 6;
    const int gwave = blockIdx.x * wavesPerBlock + waveInBlock;
    const int nwaves = gridDim.x * wavesPerBlock;

    // v slice for this lane: floats [4*lane, 4*lane+4) and [256+4*lane, ...)
    const float4* v4 = (const float4*)v;          // 128 float4
    const float4 va = v4[lane];
    const float4 vb = v4[64 + lane];

    for (int row = gwave; row < n; row += nwaves) {
        const float4* r4 = (const float4*)(vs + (size_t)row * DIM);
        float4 ra = r4[lane];        // lanes 0..63 -> bytes 0..1023 contiguous
        float4 rb = r4[64 + lane];   // bytes 1024..2047 contiguous
        float acc = ra.x * va.x;
        acc = fmaf(ra.y, va.y, acc);
        acc = fmaf(ra.z, va.z, acc);
        acc = fmaf(ra.w, va.w, acc);
        acc = fmaf(rb.x, vb.x, acc);
        acc = fmaf(rb.y, vb.y, acc);
        acc = fmaf(rb.z, vb.z, acc);
        acc = fmaf(rb.w, vb.w, acc);
        #pragma unroll
        for (int off = 32; off > 0; off >>= 1)
            acc += __shfl_xor(acc, off, 64);
        if (lane == 0) alpha[row] = acc;
    }
}

// ---------------- Kernel 2: per-block top-64 (64 blocks x 3125 elems) ----------------
__global__ __launch_bounds__(256) void topk_stage1(const float* __restrict__ alpha,
                                                   float* __restrict__ cand_val,
                                                   int* __restrict__ cand_idx,
                                                   int n, int epb) {
    __shared__ float s_val[4];
    __shared__ int   s_idx[4];
    __shared__ float s_bv;
    __shared__ int   s_bi;

    const int t = threadIdx.x;
    const int lane = t & 63;
    const int wave = t >> 6;
    const int base = blockIdx.x * epb;

    float val[SLOTS1];
    int   idx[SLOTS1];
    #pragma unroll
    for (int s = 0; s < SLOTS1; ++s) {
        int off = s * 256 + t;
        int gi = base + off;
        if (off < epb && gi < n) { val[s] = alpha[gi]; idx[s] = gi; }
        else                     { val[s] = -INFINITY; idx[s] = INT_MAX; }
    }

    for (int r = 0; r < KSEL; ++r) {
        // local max over register slots (compile-time indices only)
        float bv = val[0]; int bi = idx[0];
        #pragma unroll
        for (int s = 1; s < SLOTS1; ++s) {
            bool better = (val[s] > bv) || (val[s] == bv && idx[s] < bi);
            if (better) { bv = val[s]; bi = idx[s]; }
        }
        // wave butterfly reduce (val, idx), lower idx wins ties
        float wv = bv; int wi = bi;
        #pragma unroll
        for (int off = 32; off > 0; off >>= 1) {
            float ov = __shfl_xor(wv, off, 64);
            int   oi = __shfl_xor(wi, off, 64);
            bool better = (ov > wv) || (ov == wv && oi < wi);
            if (better) { wv = ov; wi = oi; }
        }
        if (lane == 0) { s_val[wave] = wv; s_idx[wave] = wi; }
        __syncthreads();
        if (t == 0) {
            float fv = s_val[0]; int fi = s_idx[0];
            #pragma unroll
            for (int w = 1; w < 4; ++w) {
                bool better = (s_val[w] > fv) || (s_val[w] == fv && s_idx[w] < fi);
                if (better) { fv = s_val[w]; fi = s_idx[w]; }
            }
            s_bv = fv; s_bi = fi;
            cand_val[blockIdx.x * KSEL + r] = fv;
            cand_idx[blockIdx.x * KSEL + r] = fi;
        }
        __syncthreads();
        const int winner = s_bi;
        // invalidate the winning slot (idx-match keeps all indexing static)
        #pragma unroll
        for (int s = 0; s < SLOTS1; ++s) {
            if (idx[s] == winner) { val[s] = -INFINITY; idx[s] = INT_MAX; }
        }
    }
}

// ---------------- Kernel 3: top-64 of 4096 candidates + softmax + weighted sum ----------------
__global__ __launch_bounds__(256) void topk_final(const float* __restrict__ cand_val,
                                                  const int* __restrict__ cand_idx,
                                                  const float* __restrict__ scores,
                                                  float* __restrict__ out) {
    __shared__ float s_val[4];
    __shared__ int   s_idx[4];
    __shared__ float s_bv;
    __shared__ int   s_bi;
    __shared__ float top_val[KSEL];
    __shared__ int   top_idx[KSEL];

    const int t = threadIdx.x;
    const int lane = t & 63;
    const int wave = t >> 6;

    float val[SLOTS2];
    int   idx[SLOTS2];
    #pragma unroll
    for (int s = 0; s < SLOTS2; ++s) {
        int c = s * 256 + t;
        val[s] = cand_val[c];
        idx[s] = cand_idx[c];
    }

    for (int r = 0; r < KSEL; ++r) {
        float bv = val[0]; int bi = idx[0];
        #pragma unroll
        for (int s = 1; s < SLOTS2; ++s) {
            bool better = (val[s] > bv) || (val[s] == bv && idx[s] < bi);
            if (better) { bv = val[s]; bi = idx[s]; }
        }
        float wv = bv; int wi = bi;
        #pragma unroll
        for (int off = 32; off > 0; off >>= 1) {
            float ov = __shfl_xor(wv, off, 64);
            int   oi = __shfl_xor(wi, off, 64);
            bool better = (ov > wv) || (ov == wv && oi < wi);
            if (better) { wv = ov; wi = oi; }
        }
        if (lane == 0) { s_val[wave] = wv; s_idx[wave] = wi; }
        __syncthreads();
        if (t == 0) {
            float fv = s_val[0]; int fi = s_idx[0];
            #pragma unroll
            for (int w = 1; w < 4; ++w) {
                bool better = (s_val[w] > fv) || (s_val[w] == fv && s_idx[w] < fi);
                if (better) { fv = s_val[w]; fi = s_idx[w]; }
            }
            s_bv = fv; s_bi = fi;
            top_val[r] = fv;
            top_idx[r] = fi;
        }
        __syncthreads();
        const int winner = s_bi;
        #pragma unroll
        for (int s = 0; s < SLOTS2; ++s) {
            if (idx[s] == winner) { val[s] = -INFINITY; idx[s] = INT_MAX; }
        }
    }

    // softmax over top_val + weighted sum of scores[top_idx], one wave
    if (t < 64) {
        float vv = top_val[t];
        float m = vv;
        #pragma unroll
        for (int off = 32; off > 0; off >>= 1)
            m = fmaxf(m, __shfl_xor(m, off, 64));
        float e = expf(vv - m);
        float Z = e;
        #pragma unroll
        for (int off = 32; off > 0; off >>= 1)
            Z += __shfl_xor(Z, off, 64);
        float ws = e * scores[top_idx[t]];
        float S = ws;
        #pragma unroll
        for (int off = 32; off > 0; off >>= 1)
            S += __shfl_xor(S, off, 64);
        if (t == 0) out[0] = S / Z;
    }
}

extern "C" void kernel_launch(void* const* d_in, const int* in_sizes, int n_in,
                              void* d_out, int out_size, void* d_ws, size_t ws_size,
                              hipStream_t stream) {
    const float* v      = (const float*)d_in[0];   // [512]
    const float* vs     = (const float*)d_in[1];   // [N, 512]
    const float* scores = (const float*)d_in[2];   // [N]
    float* out = (float*)d_out;

    const int n = in_sizes[2];                     // 200000
    const int epb = (n + NB1 - 1) / NB1;           // 3125

    // workspace layout (bytes): alpha[n] | cand_val[4096] | cand_idx[4096]
    char* ws = (char*)d_ws;
    float* alpha    = (float*)ws;
    size_t alpha_b  = ((size_t)n * sizeof(float) + 255) & ~(size_t)255;
    float* cand_val = (float*)(ws + alpha_b);
    int*   cand_idx = (int*)(ws + alpha_b + NB1 * KSEL * sizeof(float));

    dot_kernel<<<2048, 256, 0, stream>>>(vs, v, alpha, n);
    topk_stage1<<<NB1, 256, 0, stream>>>(alpha, cand_val, cand_idx, n, epb);
    topk_final<<<1, 256, 0, stream>>>(cand_val, cand_idx, scores, out);
}

// Round 2
// 709.239 us; speedup vs baseline: 1.0076x; 1.0076x over previous
//
#include <hip/hip_runtime.h>
#include <math.h>
#include <limits.h>

#define DIM   512
#define KSEL  64
#define NB1   64          // stage-1 blocks
#define SLOTS1 13         // ceil((N/NB1)/256) for N=200000 -> EPB=3125
#define SLOTS2 16         // (NB1*KSEL)/256 = 4096/256

// ---------------- Kernel 1: alpha[i] = dot(vs[i], v) ----------------
// 16 lanes per row, 4 rows per wave per iteration.
// Per iteration: 8 independent float4 loads/lane (8 KB in flight per wave),
// 32 FMAs, 4-step xor-reduce within 16-lane groups, one coalesced 4-dword store.
__global__ __launch_bounds__(256) void dot_kernel(const float* __restrict__ vs,
                                                  const float* __restrict__ v,
                                                  float* __restrict__ alpha,
                                                  int n) {
    const int lane = threadIdx.x & 63;
    const int sub  = lane & 15;   // position within 16-lane row-group
    const int grp  = lane >> 4;   // which of the 4 rows this lane works on
    const int waveInBlock = threadIdx.x >> 6;
    const int gwave = blockIdx.x * 4 + waveInBlock;
    const int nwaves = gridDim.x * 4;

    // v fragment: float4 index i*16+sub, i = 0..7 (covers all 512 floats per group)
    const float4* v4 = (const float4*)v;
    float4 vf[8];
    #pragma unroll
    for (int i = 0; i < 8; ++i) vf[i] = v4[i * 16 + sub];

    const int ngroups = n >> 2;   // groups of 4 rows
    for (int g = gwave; g < ngroups; g += nwaves) {
        const int row = g * 4 + grp;
        const float4* r4 = (const float4*)(vs + (size_t)row * DIM);
        float4 d[8];
        #pragma unroll
        for (int i = 0; i < 8; ++i) d[i] = r4[i * 16 + sub];   // 8 loads in flight
        float acc = 0.f;
        #pragma unroll
        for (int i = 0; i < 8; ++i) {
            acc = fmaf(d[i].x, vf[i].x, acc);
            acc = fmaf(d[i].y, vf[i].y, acc);
            acc = fmaf(d[i].z, vf[i].z, acc);
            acc = fmaf(d[i].w, vf[i].w, acc);
        }
        #pragma unroll
        for (int off = 8; off > 0; off >>= 1)
            acc += __shfl_xor(acc, off, 64);
        if (sub == 0) alpha[row] = acc;   // lanes 0,16,32,48 -> alpha[4g..4g+3]
    }

    // tail rows (n % 4 != 0) — not hit for n=200000, kept for generality
    const int tail_base = ngroups << 2;
    if (gwave == 0 && tail_base < n) {
        const int row = tail_base + grp;
        if (row < n) {
            const float4* r4 = (const float4*)(vs + (size_t)row * DIM);
            float acc = 0.f;
            #pragma unroll
            for (int i = 0; i < 8; ++i) {
                float4 dd = r4[i * 16 + sub];
                acc = fmaf(dd.x, vf[i].x, acc);
                acc = fmaf(dd.y, vf[i].y, acc);
                acc = fmaf(dd.z, vf[i].z, acc);
                acc = fmaf(dd.w, vf[i].w, acc);
            }
            #pragma unroll
            for (int off = 8; off > 0; off >>= 1)
                acc += __shfl_xor(acc, off, 64);
            if (sub == 0) alpha[row] = acc;
        }
    }
}

// ---------------- Kernel 2: per-block top-64 (64 blocks x 3125 elems) ----------------
__global__ __launch_bounds__(256) void topk_stage1(const float* __restrict__ alpha,
                                                   float* __restrict__ cand_val,
                                                   int* __restrict__ cand_idx,
                                                   int n, int epb) {
    __shared__ float s_val[4];
    __shared__ int   s_idx[4];
    __shared__ float s_bv;
    __shared__ int   s_bi;

    const int t = threadIdx.x;
    const int lane = t & 63;
    const int wave = t >> 6;
    const int base = blockIdx.x * epb;

    float val[SLOTS1];
    int   idx[SLOTS1];
    #pragma unroll
    for (int s = 0; s < SLOTS1; ++s) {
        int off = s * 256 + t;
        int gi = base + off;
        if (off < epb && gi < n) { val[s] = alpha[gi]; idx[s] = gi; }
        else                     { val[s] = -INFINITY; idx[s] = INT_MAX; }
    }

    for (int r = 0; r < KSEL; ++r) {
        // local max over register slots (compile-time indices only)
        float bv = val[0]; int bi = idx[0];
        #pragma unroll
        for (int s = 1; s < SLOTS1; ++s) {
            bool better = (val[s] > bv) || (val[s] == bv && idx[s] < bi);
            if (better) { bv = val[s]; bi = idx[s]; }
        }
        // wave butterfly reduce (val, idx), lower idx wins ties
        float wv = bv; int wi = bi;
        #pragma unroll
        for (int off = 32; off > 0; off >>= 1) {
            float ov = __shfl_xor(wv, off, 64);
            int   oi = __shfl_xor(wi, off, 64);
            bool better = (ov > wv) || (ov == wv && oi < wi);
            if (better) { wv = ov; wi = oi; }
        }
        if (lane == 0) { s_val[wave] = wv; s_idx[wave] = wi; }
        __syncthreads();
        if (t == 0) {
            float fv = s_val[0]; int fi = s_idx[0];
            #pragma unroll
            for (int w = 1; w < 4; ++w) {
                bool better = (s_val[w] > fv) || (s_val[w] == fv && s_idx[w] < fi);
                if (better) { fv = s_val[w]; fi = s_idx[w]; }
            }
            s_bv = fv; s_bi = fi;
            cand_val[blockIdx.x * KSEL + r] = fv;
            cand_idx[blockIdx.x * KSEL + r] = fi;
        }
        __syncthreads();
        const int winner = s_bi;
        // invalidate the winning slot (idx-match keeps all indexing static)
        #pragma unroll
        for (int s = 0; s < SLOTS1; ++s) {
            if (idx[s] == winner) { val[s] = -INFINITY; idx[s] = INT_MAX; }
        }
    }
}

// ---------------- Kernel 3: top-64 of 4096 candidates + softmax + weighted sum ----------------
__global__ __launch_bounds__(256) void topk_final(const float* __restrict__ cand_val,
                                                  const int* __restrict__ cand_idx,
                                                  const float* __restrict__ scores,
                                                  float* __restrict__ out) {
    __shared__ float s_val[4];
    __shared__ int   s_idx[4];
    __shared__ float s_bv;
    __shared__ int   s_bi;
    __shared__ float top_val[KSEL];
    __shared__ int   top_idx[KSEL];

    const int t = threadIdx.x;
    const int lane = t & 63;
    const int wave = t >> 6;

    float val[SLOTS2];
    int   idx[SLOTS2];
    #pragma unroll
    for (int s = 0; s < SLOTS2; ++s) {
        int c = s * 256 + t;
        val[s] = cand_val[c];
        idx[s] = cand_idx[c];
    }

    for (int r = 0; r < KSEL; ++r) {
        float bv = val[0]; int bi = idx[0];
        #pragma unroll
        for (int s = 1; s < SLOTS2; ++s) {
            bool better = (val[s] > bv) || (val[s] == bv && idx[s] < bi);
            if (better) { bv = val[s]; bi = idx[s]; }
        }
        float wv = bv; int wi = bi;
        #pragma unroll
        for (int off = 32; off > 0; off >>= 1) {
            float ov = __shfl_xor(wv, off, 64);
            int   oi = __shfl_xor(wi, off, 64);
            bool better = (ov > wv) || (ov == wv && oi < wi);
            if (better) { wv = ov; wi = oi; }
        }
        if (lane == 0) { s_val[wave] = wv; s_idx[wave] = wi; }
        __syncthreads();
        if (t == 0) {
            float fv = s_val[0]; int fi = s_idx[0];
            #pragma unroll
            for (int w = 1; w < 4; ++w) {
                bool better = (s_val[w] > fv) || (s_val[w] == fv && s_idx[w] < fi);
                if (better) { fv = s_val[w]; fi = s_idx[w]; }
            }
            s_bv = fv; s_bi = fi;
            top_val[r] = fv;
            top_idx[r] = fi;
        }
        __syncthreads();
        const int winner = s_bi;
        #pragma unroll
        for (int s = 0; s < SLOTS2; ++s) {
            if (idx[s] == winner) { val[s] = -INFINITY; idx[s] = INT_MAX; }
        }
    }

    // softmax over top_val + weighted sum of scores[top_idx], one wave
    if (t < 64) {
        float vv = top_val[t];
        float m = vv;
        #pragma unroll
        for (int off = 32; off > 0; off >>= 1)
            m = fmaxf(m, __shfl_xor(m, off, 64));
        float e = expf(vv - m);
        float Z = e;
        #pragma unroll
        for (int off = 32; off > 0; off >>= 1)
            Z += __shfl_xor(Z, off, 64);
        float ws = e * scores[top_idx[t]];
        float S = ws;
        #pragma unroll
        for (int off = 32; off > 0; off >>= 1)
            S += __shfl_xor(S, off, 64);
        if (t == 0) out[0] = S / Z;
    }
}

extern "C" void kernel_launch(void* const* d_in, const int* in_sizes, int n_in,
                              void* d_out, int out_size, void* d_ws, size_t ws_size,
                              hipStream_t stream) {
    const float* v      = (const float*)d_in[0];   // [512]
    const float* vs     = (const float*)d_in[1];   // [N, 512]
    const float* scores = (const float*)d_in[2];   // [N]
    float* out = (float*)d_out;

    const int n = in_sizes[2];                     // 200000
    const int epb = (n + NB1 - 1) / NB1;           // 3125

    // workspace layout (bytes): alpha[n] | cand_val[4096] | cand_idx[4096]
    char* ws = (char*)d_ws;
    float* alpha    = (float*)ws;
    size_t alpha_b  = ((size_t)n * sizeof(float) + 255) & ~(size_t)255;
    float* cand_val = (float*)(ws + alpha_b);
    int*   cand_idx = (int*)(ws + alpha_b + NB1 * KSEL * sizeof(float));

    dot_kernel<<<2048, 256, 0, stream>>>(vs, v, alpha, n);
    topk_stage1<<<NB1, 256, 0, stream>>>(alpha, cand_val, cand_idx, n, epb);
    topk_final<<<1, 256, 0, stream>>>(cand_val, cand_idx, scores, out);
}